// Round 1
// baseline (93.387 us; speedup 1.0000x reference)
//
#include <hip/hip_runtime.h>
#include <math.h>

#define N 512
#define DIM 256
#define NBLK 256            // threads per block
#define SCALING 10.0f
#define EPS 1e-12f

// One block per anchor `a`:
//  1. load feat[a] + labels into LDS
//  2. compute distance row drow[j] = ||feat_a - feat_j|| for all j (float4 loads)
//  3. compact positive / negative distance lists in LDS
//  4. pos x neg sigmoid double loop, block-reduce partial sum
__global__ __launch_bounds__(NBLK) void anchor_kernel(
    const float* __restrict__ feat, const int* __restrict__ y,
    float* __restrict__ block_sum, float* __restrict__ block_cnt)
{
    __shared__ float fa[DIM];
    __shared__ float drow[N];
    __shared__ int   ysh[N];
    __shared__ float pos_d[N];
    __shared__ float neg_d[N];
    __shared__ int   n_pos, n_neg;
    __shared__ float red[NBLK];

    const int a   = blockIdx.x;
    const int tid = threadIdx.x;

    // --- stage anchor row + labels ---
    fa[tid] = feat[a * DIM + tid];          // DIM == NBLK == 256
    ysh[tid]       = y[tid];
    ysh[tid + 256] = y[tid + 256];
    if (tid == 0) { n_pos = 0; n_neg = 0; }
    __syncthreads();

    const int ya = ysh[a];

    // --- distance row: each thread handles rows tid and tid+256 ---
    const float4* feat4 = reinterpret_cast<const float4*>(feat);
    #pragma unroll
    for (int r = 0; r < 2; ++r) {
        const int j = tid + r * 256;
        const float4* rowj = feat4 + j * (DIM / 4);
        float acc = 0.0f;
        #pragma unroll 8
        for (int k = 0; k < DIM / 4; ++k) {
            float4 v = rowj[k];
            float d0 = v.x - fa[4 * k + 0];
            float d1 = v.y - fa[4 * k + 1];
            float d2 = v.z - fa[4 * k + 2];
            float d3 = v.w - fa[4 * k + 3];
            acc += d0 * d0 + d1 * d1 + d2 * d2 + d3 * d3;
        }
        drow[j] = sqrtf(fmaxf(acc, EPS));
    }
    __syncthreads();

    // --- compact pos / neg lists (order irrelevant for the sum) ---
    #pragma unroll
    for (int r = 0; r < 2; ++r) {
        const int j = tid + r * 256;
        const int yj = ysh[j];
        if (yj == ya) {
            if (j != a) {
                int idx = atomicAdd(&n_pos, 1);
                pos_d[idx] = drow[j];
            }
        } else {
            int idx = atomicAdd(&n_neg, 1);
            neg_d[idx] = drow[j];
        }
    }
    __syncthreads();

    const int np = n_pos;
    const int nn = n_neg;

    // --- sigmoid over valid (p, n) pairs ---
    float acc = 0.0f;
    for (int p = 0; p < np; ++p) {
        const float dp = pos_d[p];
        for (int n = tid; n < nn; n += NBLK) {
            float x = SCALING * (dp - neg_d[n]);
            acc += 1.0f / (1.0f + __expf(-x));
        }
    }

    // --- block reduce ---
    red[tid] = acc;
    __syncthreads();
    for (int s = NBLK / 2; s > 0; s >>= 1) {
        if (tid < s) red[tid] += red[tid + s];
        __syncthreads();
    }
    if (tid == 0) {
        block_sum[a] = red[0];
        block_cnt[a] = (float)(np * nn);
    }
}

// Single-block deterministic reduction of the 512 per-anchor partials.
__global__ __launch_bounds__(NBLK) void finalize_kernel(
    const float* __restrict__ block_sum, const float* __restrict__ block_cnt,
    float* __restrict__ out)
{
    __shared__ double s_sum[NBLK];
    __shared__ double s_cnt[NBLK];
    const int tid = threadIdx.x;
    s_sum[tid] = (double)block_sum[tid] + (double)block_sum[tid + 256];
    s_cnt[tid] = (double)block_cnt[tid] + (double)block_cnt[tid + 256];
    __syncthreads();
    for (int s = NBLK / 2; s > 0; s >>= 1) {
        if (tid < s) {
            s_sum[tid] += s_sum[tid + s];
            s_cnt[tid] += s_cnt[tid + s];
        }
        __syncthreads();
    }
    if (tid == 0) out[0] = (float)(s_sum[0] / s_cnt[0]);
}

extern "C" void kernel_launch(void* const* d_in, const int* in_sizes, int n_in,
                              void* d_out, int out_size, void* d_ws, size_t ws_size,
                              hipStream_t stream) {
    const float* feat = (const float*)d_in[0];
    // d_in[1] = logits: unused by the loss
    const int* y = (const int*)d_in[2];

    float* block_sum = (float*)d_ws;          // N floats
    float* block_cnt = block_sum + N;         // N floats
    float* out = (float*)d_out;

    anchor_kernel<<<N, NBLK, 0, stream>>>(feat, y, block_sum, block_cnt);
    finalize_kernel<<<1, NBLK, 0, stream>>>(block_sum, block_cnt, out);
}

// Round 2
// 84.404 us; speedup vs baseline: 1.1064x; 1.1064x over previous
//
#include <hip/hip_runtime.h>
#include <math.h>

#define N 512
#define DIM 256
#define NBLK 256            // threads per block
#define APB 2               // anchors per block
#define SCALING 10.0f
#define EPS 1e-12f

// One block per APB anchors:
//  1. load anchor rows + labels into LDS
//  2. one pass over all feat rows: compute ||feat_a - feat_j|| for both anchors
//     from a single float4 load of row j, classify into pos/neg lists directly
//  3. pos x neg sigmoid loops for both anchors, wave-shuffle block reduce
__global__ __launch_bounds__(NBLK) void anchor_kernel(
    const float* __restrict__ feat, const int* __restrict__ y,
    float* __restrict__ block_sum, float* __restrict__ block_cnt)
{
    __shared__ float fa[APB][DIM];
    __shared__ int   ysh[N];
    __shared__ float pos_d[APB][N];
    __shared__ float neg_d[APB][N];
    __shared__ int   n_pos[APB], n_neg[APB];
    __shared__ float red[NBLK / 64];

    const int a0  = blockIdx.x * APB;
    const int tid = threadIdx.x;

    // --- stage anchor rows + labels ---
    #pragma unroll
    for (int q = 0; q < APB; ++q)
        fa[q][tid] = feat[(a0 + q) * DIM + tid];    // DIM == NBLK == 256
    ysh[tid]       = y[tid];
    ysh[tid + 256] = y[tid + 256];
    if (tid < APB) { n_pos[tid] = 0; n_neg[tid] = 0; }
    __syncthreads();

    const int ya0 = ysh[a0];
    const int ya1 = ysh[a0 + 1];

    // --- distance pass: each thread handles rows tid and tid+256 ---
    const float4* feat4 = reinterpret_cast<const float4*>(feat);
    #pragma unroll
    for (int r = 0; r < 2; ++r) {
        const int j = tid + r * 256;
        const float4* rowj = feat4 + j * (DIM / 4);
        float acc0 = 0.0f, acc1 = 0.0f;
        #pragma unroll 8
        for (int k = 0; k < DIM / 4; ++k) {
            float4 v = rowj[k];
            float e0, e1, e2, e3;
            e0 = v.x - fa[0][4 * k + 0];
            e1 = v.y - fa[0][4 * k + 1];
            e2 = v.z - fa[0][4 * k + 2];
            e3 = v.w - fa[0][4 * k + 3];
            acc0 += e0 * e0 + e1 * e1 + e2 * e2 + e3 * e3;
            e0 = v.x - fa[1][4 * k + 0];
            e1 = v.y - fa[1][4 * k + 1];
            e2 = v.z - fa[1][4 * k + 2];
            e3 = v.w - fa[1][4 * k + 3];
            acc1 += e0 * e0 + e1 * e1 + e2 * e2 + e3 * e3;
        }
        const float d0 = sqrtf(fmaxf(acc0, EPS));
        const float d1 = sqrtf(fmaxf(acc1, EPS));
        const int yj = ysh[j];
        // anchor 0
        if (yj == ya0) {
            if (j != a0) { int i = atomicAdd(&n_pos[0], 1); pos_d[0][i] = d0; }
        } else {
            int i = atomicAdd(&n_neg[0], 1); neg_d[0][i] = d0;
        }
        // anchor 1
        if (yj == ya1) {
            if (j != a0 + 1) { int i = atomicAdd(&n_pos[1], 1); pos_d[1][i] = d1; }
        } else {
            int i = atomicAdd(&n_neg[1], 1); neg_d[1][i] = d1;
        }
    }
    __syncthreads();

    // --- sigmoid over valid (p, n) pairs, both anchors ---
    float acc = 0.0f;
    int   cnt = 0;
    #pragma unroll
    for (int q = 0; q < APB; ++q) {
        const int np = n_pos[q];
        const int nn = n_neg[q];
        cnt += np * nn;
        for (int p = 0; p < np; ++p) {
            const float dp = pos_d[q][p];
            for (int n = tid; n < nn; n += NBLK) {
                float x = SCALING * (dp - neg_d[q][n]);
                acc += 1.0f / (1.0f + __expf(-x));
            }
        }
    }

    // --- wave shuffle reduce, then cross-wave via LDS ---
    #pragma unroll
    for (int s = 32; s > 0; s >>= 1)
        acc += __shfl_down(acc, s, 64);
    if ((tid & 63) == 0) red[tid >> 6] = acc;
    __syncthreads();
    if (tid == 0) {
        float t = red[0] + red[1] + red[2] + red[3];
        block_sum[blockIdx.x] = t;
        block_cnt[blockIdx.x] = (float)cnt;
    }
}

// Single-block deterministic reduction of the 256 per-block partials.
__global__ __launch_bounds__(NBLK) void finalize_kernel(
    const float* __restrict__ block_sum, const float* __restrict__ block_cnt,
    float* __restrict__ out)
{
    __shared__ double s_sum[NBLK];
    __shared__ double s_cnt[NBLK];
    const int tid = threadIdx.x;
    s_sum[tid] = (double)block_sum[tid];
    s_cnt[tid] = (double)block_cnt[tid];
    __syncthreads();
    for (int s = NBLK / 2; s > 0; s >>= 1) {
        if (tid < s) {
            s_sum[tid] += s_sum[tid + s];
            s_cnt[tid] += s_cnt[tid + s];
        }
        __syncthreads();
    }
    if (tid == 0) out[0] = (float)(s_sum[0] / s_cnt[0]);
}

extern "C" void kernel_launch(void* const* d_in, const int* in_sizes, int n_in,
                              void* d_out, int out_size, void* d_ws, size_t ws_size,
                              hipStream_t stream) {
    const float* feat = (const float*)d_in[0];
    // d_in[1] = logits: unused by the loss
    const int* y = (const int*)d_in[2];

    float* block_sum = (float*)d_ws;              // N/APB floats
    float* block_cnt = block_sum + (N / APB);     // N/APB floats
    float* out = (float*)d_out;

    anchor_kernel<<<N / APB, NBLK, 0, stream>>>(feat, y, block_sum, block_cnt);
    finalize_kernel<<<1, NBLK, 0, stream>>>(block_sum, block_cnt, out);
}